// Round 1
// baseline (3302.710 us; speedup 1.0000x reference)
//
#include <hip/hip_runtime.h>
#include <math.h>

#define NNODES 100000
#define NEDGES 1600000
#define NBATCH 64

// One thread per edge. Node i owns edges 16i..16i+15 (dst = repeat(arange(N),16)),
// so the 16 lanes of a 16-lane group all work on the same destination node and
// the segment_max is a 4-step shfl_xor reduction. Second GEMM is done as a
// rank-8 update into z[O] accumulators so the hidden vector y is never fully
// materialized (keeps VGPRs under control for the 128-wide layer 3).
template<int CIN, int H, int O>
__global__ __launch_bounds__(256, 2)
void layer_k(const float* __restrict__ hin, const float* __restrict__ pos,
             const int* __restrict__ srcArr,
             const float* __restrict__ wa, const float* __restrict__ ba,
             const float* __restrict__ wb, const float* __restrict__ bb,
             float* __restrict__ hout)
{
    constexpr int K = CIN + 3;
    const int e    = blockIdx.x * 256 + threadIdx.x;   // grid sized exactly E
    const int node = e >> 4;
    const int src  = srcArr[e];

    float x[K];
    if constexpr (CIN == 3) {
        const float ps0 = pos[src*3+0], ps1 = pos[src*3+1], ps2 = pos[src*3+2];
        x[0] = ps0; x[1] = ps1; x[2] = ps2;
        x[3] = ps0 - pos[node*3+0];
        x[4] = ps1 - pos[node*3+1];
        x[5] = ps2 - pos[node*3+2];
    } else {
        const float4* hp = reinterpret_cast<const float4*>(hin + (size_t)src * CIN);
        #pragma unroll
        for (int c = 0; c < CIN/4; ++c) {
            const float4 v = hp[c];
            x[4*c+0] = v.x; x[4*c+1] = v.y; x[4*c+2] = v.z; x[4*c+3] = v.w;
        }
        x[CIN+0] = pos[src*3+0] - pos[node*3+0];
        x[CIN+1] = pos[src*3+1] - pos[node*3+1];
        x[CIN+2] = pos[src*3+2] - pos[node*3+2];
    }

    float z[O];
    #pragma unroll
    for (int o = 0; o < O; ++o) z[o] = bb[o];

    #pragma unroll 1
    for (int h0 = 0; h0 < H; h0 += 8) {
        float ya[8];
        #pragma unroll
        for (int j = 0; j < 8; ++j) {
            float acc = ba[h0+j];
            #pragma unroll
            for (int k = 0; k < K; ++k)
                acc = fmaf(x[k], wa[k*H + h0 + j], acc);
            ya[j] = fmaxf(acc, 0.f);
        }
        #pragma unroll
        for (int j = 0; j < 8; ++j) {
            #pragma unroll
            for (int o = 0; o < O; ++o)
                z[o] = fmaf(ya[j], wb[(h0+j)*O + o], z[o]);
        }
    }

    // segment_max over the 16 lanes of this node, then outer relu.
    const int lane = threadIdx.x & 15;
    float keep[O/16];
    #pragma unroll
    for (int o = 0; o < O; ++o) {
        float v = z[o];
        #pragma unroll
        for (int s = 1; s < 16; s <<= 1)
            v = fmaxf(v, __shfl_xor(v, s));
        if ((o & 15) == lane) keep[o >> 4] = v;
    }
    #pragma unroll
    for (int jj = 0; jj < O/16; ++jj)
        hout[(size_t)node * O + jj*16 + lane] = fmaxf(keep[jj], 0.f);
}

__global__ void zero_k(float* __restrict__ p, int n)
{
    const int i = blockIdx.x * 256 + threadIdx.x;
    if (i < n) p[i] = 0.f;
}

__global__ void pool_k(const float* __restrict__ h3, const int* __restrict__ batch,
                       float* __restrict__ pooled, float* __restrict__ counts)
{
    const int tid = blockIdx.x * 256 + threadIdx.x;   // N*128 threads exactly
    const int n = tid >> 7, c = tid & 127;
    const int b = batch[n];
    atomicAdd(pooled + b*128 + c, h3[tid]);
    if (c == 0) atomicAdd(counts + b, 1.f);
}

__global__ void reg_k(const float* __restrict__ pooled, const float* __restrict__ counts,
                      const float* __restrict__ wr1, const float* __restrict__ br1,
                      const float* __restrict__ wr2, const float* __restrict__ br2,
                      float* __restrict__ out)
{
    const int b = blockIdx.x;     // 64 blocks
    const int h = threadIdx.x;    // 64 threads = hidden dim
    const float rc = 1.f / fmaxf(counts[b], 1.f);
    float acc = br1[h];
    #pragma unroll
    for (int k = 0; k < 128; ++k)
        acc = fmaf(pooled[b*128 + k] * rc, wr1[k*64 + h], acc);
    float v = acc * wr2[h];       // no activation between regressor linears
    #pragma unroll
    for (int s = 1; s < 64; s <<= 1)
        v += __shfl_xor(v, s);
    if (h == 0) out[b] = 1.f / (1.f + expf(-(v + br2[0])));
}

extern "C" void kernel_launch(void* const* d_in, const int* in_sizes, int n_in,
                              void* d_out, int out_size, void* d_ws, size_t ws_size,
                              hipStream_t stream)
{
    const float* pos   = (const float*)d_in[0];
    const int*   eidx  = (const int*)d_in[1];    // [2,E]; row 0 = src
    const int*   batch = (const int*)d_in[2];
    // d_in[3] = timestep: unused by the reference
    const float *w1a = (const float*)d_in[4],  *b1a = (const float*)d_in[5];
    const float *w1b = (const float*)d_in[6],  *b1b = (const float*)d_in[7];
    const float *w2a = (const float*)d_in[8],  *b2a = (const float*)d_in[9];
    const float *w2b = (const float*)d_in[10], *b2b = (const float*)d_in[11];
    const float *w3a = (const float*)d_in[12], *b3a = (const float*)d_in[13];
    const float *w3b = (const float*)d_in[14], *b3b = (const float*)d_in[15];
    const float *wr1 = (const float*)d_in[16], *br1 = (const float*)d_in[17];
    const float *wr2 = (const float*)d_in[18], *br2 = (const float*)d_in[19];
    const int* srcArr = eidx;                    // row 0

    float* ws     = (float*)d_ws;
    float* h1     = ws;                                  // N*64
    float* h2     = h1 + (size_t)NNODES * 64;            // N*64
    float* h3     = h2 + (size_t)NNODES * 64;            // N*128
    float* pooled = h3 + (size_t)NNODES * 128;           // B*128
    float* counts = pooled + NBATCH * 128;               // B
    float* out    = (float*)d_out;

    const dim3 blk(256);
    layer_k<3,  64, 64 ><<<NEDGES/256, blk, 0, stream>>>(pos, pos, srcArr, w1a, b1a, w1b, b1b, h1);
    layer_k<64, 64, 64 ><<<NEDGES/256, blk, 0, stream>>>(h1,  pos, srcArr, w2a, b2a, w2b, b2b, h2);
    layer_k<64, 128,128><<<NEDGES/256, blk, 0, stream>>>(h2,  pos, srcArr, w3a, b3a, w3b, b3b, h3);
    zero_k<<<(NBATCH*128 + NBATCH + 255)/256, blk, 0, stream>>>(pooled, NBATCH*128 + NBATCH);
    pool_k<<<(NNODES*128)/256, blk, 0, stream>>>(h3, batch, pooled, counts);
    reg_k <<<NBATCH, dim3(64), 0, stream>>>(pooled, counts, wr1, br1, wr2, br2, out);
}

// Round 2
// 2384.958 us; speedup vs baseline: 1.3848x; 1.3848x over previous
//
#include <hip/hip_runtime.h>
#include <math.h>

#define NNODES 100000
#define NEDGES 1600000
#define NBATCH 64

// One thread per edge. Node i owns edges 16i..16i+15 (dst = repeat(arange(N),16)),
// so the 16 lanes of a 16-lane group share one destination node and segment_max
// is a 4-step shfl_xor reduction. Second GEMM is a rank-8 update into ONUM
// z-accumulators; ONUM is capped at 64 (layer 3 runs as two output-half passes)
// so x[K]+z[ONUM] stays ~150 VGPRs -> no spills / AGPR shuffling.
template<int CIN, int H, int O, int ONUM>
__global__ __launch_bounds__(256, 2)
void layer_k(const float* __restrict__ hin, const float* __restrict__ pos,
             const int* __restrict__ srcArr,
             const float* __restrict__ wa, const float* __restrict__ ba,
             const float* __restrict__ wb, const float* __restrict__ bb,
             float* __restrict__ hout, int ooff)
{
    constexpr int K = CIN + 3;
    const int e    = blockIdx.x * 256 + threadIdx.x;   // grid sized exactly E
    const int node = e >> 4;
    const int src  = srcArr[e];

    float x[K];
    if constexpr (CIN == 3) {
        const float ps0 = pos[src*3+0], ps1 = pos[src*3+1], ps2 = pos[src*3+2];
        x[0] = ps0; x[1] = ps1; x[2] = ps2;
        x[3] = ps0 - pos[node*3+0];
        x[4] = ps1 - pos[node*3+1];
        x[5] = ps2 - pos[node*3+2];
    } else {
        const float4* hp = reinterpret_cast<const float4*>(hin + (size_t)src * CIN);
        #pragma unroll
        for (int c = 0; c < CIN/4; ++c) {
            const float4 v = hp[c];
            x[4*c+0] = v.x; x[4*c+1] = v.y; x[4*c+2] = v.z; x[4*c+3] = v.w;
        }
        x[CIN+0] = pos[src*3+0] - pos[node*3+0];
        x[CIN+1] = pos[src*3+1] - pos[node*3+1];
        x[CIN+2] = pos[src*3+2] - pos[node*3+2];
    }

    float z[ONUM];
    #pragma unroll
    for (int o = 0; o < ONUM; ++o) z[o] = bb[ooff + o];

    #pragma unroll 1
    for (int h0 = 0; h0 < H; h0 += 8) {
        float ya[8];
        #pragma unroll
        for (int j = 0; j < 8; ++j) {
            float acc = ba[h0+j];
            #pragma unroll
            for (int k = 0; k < K; ++k)
                acc = fmaf(x[k], wa[k*H + h0 + j], acc);   // 8 consecutive h -> s_load_dwordx8
            ya[j] = fmaxf(acc, 0.f);
        }
        #pragma unroll
        for (int j = 0; j < 8; ++j) {
            #pragma unroll
            for (int o = 0; o < ONUM; ++o)
                z[o] = fmaf(ya[j], wb[(h0+j)*O + ooff + o], z[o]);  // contiguous row chunk
        }
    }

    // segment_max over the 16 lanes of this node, then outer relu.
    const int lane = threadIdx.x & 15;
    float keep[ONUM/16];
    #pragma unroll
    for (int o = 0; o < ONUM; ++o) {
        float v = z[o];
        #pragma unroll
        for (int s = 1; s < 16; s <<= 1)
            v = fmaxf(v, __shfl_xor(v, s));
        if ((o & 15) == lane) keep[o >> 4] = v;
    }
    #pragma unroll
    for (int jj = 0; jj < ONUM/16; ++jj)
        hout[(size_t)node * O + ooff + jj*16 + lane] = fmaxf(keep[jj], 0.f);
}

__global__ void zero_k(float* __restrict__ p, int n)
{
    const int i = blockIdx.x * 256 + threadIdx.x;
    if (i < n) p[i] = 0.f;
}

// batch is SORTED: accumulate runs in registers, one atomic per batch-change.
// Block covers 128 nodes: thread = (channel c in [0,128), half in {0,1}); each
// half sums 64 consecutive nodes per channel.
__global__ void pool_k(const float* __restrict__ h3, const int* __restrict__ batch,
                       float* __restrict__ pooled, float* __restrict__ counts)
{
    const int c    = threadIdx.x & 127;
    const int half = threadIdx.x >> 7;
    const int nbeg = blockIdx.x * 128 + half * 64;
    if (nbeg >= NNODES) return;
    const int nend = min(nbeg + 64, NNODES);

    int   cur = batch[nbeg];
    float acc = 0.f;
    int   runlen = 0;
    for (int n = nbeg; n < nend; ++n) {
        const int b = batch[n];               // uniform across the 128-thread half
        if (b != cur) {
            atomicAdd(pooled + cur*128 + c, acc);
            if (c == 0) atomicAdd(counts + cur, (float)runlen);
            acc = 0.f; runlen = 0; cur = b;
        }
        acc += h3[(size_t)n * 128 + c];
        ++runlen;
    }
    atomicAdd(pooled + cur*128 + c, acc);
    if (c == 0) atomicAdd(counts + cur, (float)runlen);
}

__global__ void reg_k(const float* __restrict__ pooled, const float* __restrict__ counts,
                      const float* __restrict__ wr1, const float* __restrict__ br1,
                      const float* __restrict__ wr2, const float* __restrict__ br2,
                      float* __restrict__ out)
{
    const int b = blockIdx.x;     // 64 blocks
    const int h = threadIdx.x;    // 64 threads = hidden dim
    const float rc = 1.f / fmaxf(counts[b], 1.f);
    float acc = br1[h];
    #pragma unroll
    for (int k = 0; k < 128; ++k)
        acc = fmaf(pooled[b*128 + k] * rc, wr1[k*64 + h], acc);
    float v = acc * wr2[h];       // no activation between regressor linears
    #pragma unroll
    for (int s = 1; s < 64; s <<= 1)
        v += __shfl_xor(v, s);
    if (h == 0) out[b] = 1.f / (1.f + expf(-(v + br2[0])));
}

extern "C" void kernel_launch(void* const* d_in, const int* in_sizes, int n_in,
                              void* d_out, int out_size, void* d_ws, size_t ws_size,
                              hipStream_t stream)
{
    const float* pos   = (const float*)d_in[0];
    const int*   eidx  = (const int*)d_in[1];    // [2,E]; row 0 = src
    const int*   batch = (const int*)d_in[2];
    // d_in[3] = timestep: unused by the reference
    const float *w1a = (const float*)d_in[4],  *b1a = (const float*)d_in[5];
    const float *w1b = (const float*)d_in[6],  *b1b = (const float*)d_in[7];
    const float *w2a = (const float*)d_in[8],  *b2a = (const float*)d_in[9];
    const float *w2b = (const float*)d_in[10], *b2b = (const float*)d_in[11];
    const float *w3a = (const float*)d_in[12], *b3a = (const float*)d_in[13];
    const float *w3b = (const float*)d_in[14], *b3b = (const float*)d_in[15];
    const float *wr1 = (const float*)d_in[16], *br1 = (const float*)d_in[17];
    const float *wr2 = (const float*)d_in[18], *br2 = (const float*)d_in[19];
    const int* srcArr = eidx;                    // row 0

    float* ws     = (float*)d_ws;
    float* h1     = ws;                                  // N*64
    float* h2     = h1 + (size_t)NNODES * 64;            // N*64
    float* h3     = h2 + (size_t)NNODES * 64;            // N*128
    float* pooled = h3 + (size_t)NNODES * 128;           // B*128
    float* counts = pooled + NBATCH * 128;               // B
    float* out    = (float*)d_out;

    const dim3 blk(256);
    layer_k<3,  64, 64, 64><<<NEDGES/256, blk, 0, stream>>>(pos, pos, srcArr, w1a, b1a, w1b, b1b, h1, 0);
    layer_k<64, 64, 64, 64><<<NEDGES/256, blk, 0, stream>>>(h1,  pos, srcArr, w2a, b2a, w2b, b2b, h2, 0);
    layer_k<64, 128,128,64><<<NEDGES/256, blk, 0, stream>>>(h2,  pos, srcArr, w3a, b3a, w3b, b3b, h3, 0);
    layer_k<64, 128,128,64><<<NEDGES/256, blk, 0, stream>>>(h2,  pos, srcArr, w3a, b3a, w3b, b3b, h3, 64);
    zero_k<<<(NBATCH*128 + NBATCH + 255)/256, blk, 0, stream>>>(pooled, NBATCH*128 + NBATCH);
    pool_k<<<(NNODES + 127)/128, blk, 0, stream>>>(h3, batch, pooled, counts);
    reg_k <<<NBATCH, dim3(64), 0, stream>>>(pooled, counts, wr1, br1, wr2, br2, out);
}

// Round 3
// 869.168 us; speedup vs baseline: 3.7999x; 2.7440x over previous
//
#include <hip/hip_runtime.h>
#include <math.h>

#define NNODES 100000
#define NEDGES 1600000
#define NBATCH 64
#define NTILES (NEDGES/64)   // 25000 tiles of 64 edges (4 nodes)

typedef __attribute__((ext_vector_type(8))) short  short8;
typedef __attribute__((ext_vector_type(4))) short  short4v;
typedef __attribute__((ext_vector_type(4))) float  float4v;

__device__ __forceinline__ short f2bf(float f) {           // RTNE fp32->bf16
    unsigned u = __builtin_bit_cast(unsigned, f);
    u += 0x7fffu + ((u >> 16) & 1u);
    return (short)(u >> 16);
}
__device__ __forceinline__ float b2f(short s) {
    unsigned u = ((unsigned)(unsigned short)s) << 16;
    return __builtin_bit_cast(float, u);
}

// Split-bf16 MFMA layer. Orientation swapped: A = W^T (M = out-dim), B = x^T
// (N = edges). D lane layout (m89-verified): col(=edge) = lane&15,
// row(=out) = (lane>>4)*4 + reg. Weights held in VGPR frags for the whole
// block (persistent grid-stride loop); only activations stream through LDS.
// Precision: w = wh+wl, x = xh+xl (bf16 hi/lo); accumulate wh*xh + wl*xh +
// wh*xl in fp32 -> ~2^-17 relative error.
template<int CIN, int H, int O>
__global__ __launch_bounds__(256, 2)
void layer_mfma(const float* __restrict__ hin, const float* __restrict__ pos,
                const int* __restrict__ srcArr,
                const float* __restrict__ wa, const float* __restrict__ ba,
                const float* __restrict__ wb, const float* __restrict__ bb,
                float* __restrict__ hout)
{
    constexpr int K1   = CIN + 3;
    constexpr int S1   = ((K1 + 31) / 32) * 32;  // padded K of GEMM1
    constexpr int NS1  = S1 / 32;                // phys k-steps GEMM1
    constexpr int MPW1 = H / 64;                 // m-tiles per wave, GEMM1
    constexpr int NS2  = H / 32;                 // phys k-steps GEMM2
    constexpr int MPW2 = O / 64;
    constexpr int RSX  = 2 * S1 + 8;             // x' row stride (shorts), +8 antipodal-bank pad
    constexpr int RSY  = 2 * H + 8;

    __shared__ short smem[64 * RSX + 64 * RSY];
    short* xs = smem;            // [64 edges][xh(S1) | xl(S1) | pad]
    short* ys = smem + 64 * RSX; // [64 edges][yh(H)  | yl(H)  | pad]

    const int tid  = threadIdx.x;
    const int lane = tid & 63;
    const int w    = tid >> 6;   // wave id 0..3
    const int g    = lane >> 4;  // k-group
    const int c    = lane & 15;

    // Zero all of LDS once: K-pad columns must read as 0; data columns are
    // rewritten every tile.
    {
        short4v z4 = (short4v)0;
        for (int i = tid; i < (64*RSX + 64*RSY)/4; i += 256)
            ((short4v*)smem)[i] = z4;
    }

    // ---- build persistent weight fragments (A-operand: row = lane&15) ----
    short8 wah[MPW1][NS1], wal[MPW1][NS1];
    float  bav[MPW1][4];
    #pragma unroll
    for (int mi = 0; mi < MPW1; ++mi) {
        const int mt = mi*4 + w;
        const int h  = mt*16 + c;
        #pragma unroll
        for (int pk = 0; pk < NS1; ++pk) {
            short8 fh, fl;
            #pragma unroll
            for (int j = 0; j < 8; ++j) {
                const int k = pk*32 + g*8 + j;
                float f = (k < K1) ? wa[k*H + h] : 0.f;
                short hi = f2bf(f);
                fh[j] = hi;
                fl[j] = f2bf(f - b2f(hi));
            }
            wah[mi][pk] = fh; wal[mi][pk] = fl;
        }
        #pragma unroll
        for (int r = 0; r < 4; ++r) bav[mi][r] = ba[mt*16 + g*4 + r];
    }
    short8 wbh[MPW2][NS2], wbl[MPW2][NS2];
    float  bbv[MPW2][4];
    #pragma unroll
    for (int mi = 0; mi < MPW2; ++mi) {
        const int mt = mi*4 + w;
        const int o  = mt*16 + c;
        #pragma unroll
        for (int pk = 0; pk < NS2; ++pk) {
            short8 fh, fl;
            #pragma unroll
            for (int j = 0; j < 8; ++j) {
                const int k = pk*32 + g*8 + j;   // k < H always
                float f = wb[k*O + o];
                short hi = f2bf(f);
                fh[j] = hi;
                fl[j] = f2bf(f - b2f(hi));
            }
            wbh[mi][pk] = fh; wbl[mi][pk] = fl;
        }
        #pragma unroll
        for (int r = 0; r < 4; ++r) bbv[mi][r] = bb[mt*16 + g*4 + r];
    }
    __syncthreads();

    const int e   = tid & 63;    // edge-in-tile this thread stages
    const int rep = tid >> 6;

    for (int tile = blockIdx.x; tile < NTILES; tile += gridDim.x) {
        // ---- stage x' = split(concat(h[src], pos[src]-pos[dst])) ----
        {
            const int edge = tile*64 + e;
            const int src  = srcArr[edge];
            const int node = edge >> 4;
            if constexpr (CIN == 3) {
                if (rep == 0) {
                    float v[6];
                    v[0] = pos[src*3+0]; v[1] = pos[src*3+1]; v[2] = pos[src*3+2];
                    v[3] = v[0] - pos[node*3+0];
                    v[4] = v[1] - pos[node*3+1];
                    v[5] = v[2] - pos[node*3+2];
                    short4v h0, l0, h1, l1;
                    #pragma unroll
                    for (int j = 0; j < 4; ++j) { short hi=f2bf(v[j]); h0[j]=hi; l0[j]=f2bf(v[j]-b2f(hi)); }
                    #pragma unroll
                    for (int j = 0; j < 2; ++j) { short hi=f2bf(v[4+j]); h1[j]=hi; l1[j]=f2bf(v[4+j]-b2f(hi)); }
                    h1[2]=0; h1[3]=0; l1[2]=0; l1[3]=0;
                    *(short4v*)(xs + e*RSX + 0)      = h0;
                    *(short4v*)(xs + e*RSX + 4)      = h1;
                    *(short4v*)(xs + e*RSX + S1 + 0) = l0;
                    *(short4v*)(xs + e*RSX + S1 + 4) = l1;
                }
            } else {
                #pragma unroll
                for (int i = 0; i < CIN/16; ++i) {
                    const int cch = rep + 4*i;           // float4 chunk of h-row
                    float4v v = *(const float4v*)(hin + (size_t)src*CIN + cch*4);
                    short4v hv, lv;
                    #pragma unroll
                    for (int j = 0; j < 4; ++j) { short hi=f2bf(v[j]); hv[j]=hi; lv[j]=f2bf(v[j]-b2f(hi)); }
                    *(short4v*)(xs + e*RSX + cch*4)      = hv;
                    *(short4v*)(xs + e*RSX + S1 + cch*4) = lv;
                }
                if (rep == 0) {
                    float d0 = pos[src*3+0]-pos[node*3+0];
                    float d1 = pos[src*3+1]-pos[node*3+1];
                    float d2 = pos[src*3+2]-pos[node*3+2];
                    short4v hv, lv; short hi;
                    hi=f2bf(d0); hv[0]=hi; lv[0]=f2bf(d0-b2f(hi));
                    hi=f2bf(d1); hv[1]=hi; lv[1]=f2bf(d1-b2f(hi));
                    hi=f2bf(d2); hv[2]=hi; lv[2]=f2bf(d2-b2f(hi));
                    hv[3]=0; lv[3]=0;
                    *(short4v*)(xs + e*RSX + CIN)      = hv;
                    *(short4v*)(xs + e*RSX + S1 + CIN) = lv;
                }
            }
        }
        __syncthreads();

        // ---- GEMM1: C1[h][edge] = wa^T x + ba ----
        float4v C1[MPW1][4];
        #pragma unroll
        for (int mi = 0; mi < MPW1; ++mi)
            #pragma unroll
            for (int n = 0; n < 4; ++n)
                #pragma unroll
                for (int r = 0; r < 4; ++r) C1[mi][n][r] = bav[mi][r];
        #pragma unroll
        for (int pk = 0; pk < NS1; ++pk)
            #pragma unroll
            for (int n = 0; n < 4; ++n) {
                const short* base = xs + (n*16 + c)*RSX + pk*32 + g*8;
                short8 xh = *(const short8*)base;
                short8 xl = *(const short8*)(base + S1);
                #pragma unroll
                for (int mi = 0; mi < MPW1; ++mi) {
                    C1[mi][n] = __builtin_amdgcn_mfma_f32_16x16x32_bf16(wah[mi][pk], xh, C1[mi][n], 0,0,0);
                    C1[mi][n] = __builtin_amdgcn_mfma_f32_16x16x32_bf16(wal[mi][pk], xh, C1[mi][n], 0,0,0);
                    C1[mi][n] = __builtin_amdgcn_mfma_f32_16x16x32_bf16(wah[mi][pk], xl, C1[mi][n], 0,0,0);
                }
            }
        // epilogue1: relu -> split -> y' LDS (lane holds 4 consecutive h)
        #pragma unroll
        for (int mi = 0; mi < MPW1; ++mi) {
            const int mt = mi*4 + w;
            #pragma unroll
            for (int n = 0; n < 4; ++n) {
                short4v hv, lv;
                #pragma unroll
                for (int r = 0; r < 4; ++r) {
                    float y = fmaxf(C1[mi][n][r], 0.f);
                    short hi = f2bf(y);
                    hv[r] = hi; lv[r] = f2bf(y - b2f(hi));
                }
                short* yb = ys + (n*16 + c)*RSY + mt*16 + g*4;
                *(short4v*)yb       = hv;
                *(short4v*)(yb + H) = lv;
            }
        }
        __syncthreads();

        // ---- GEMM2: C2[o][edge] = wb^T y + bb ----
        float4v C2[MPW2][4];
        #pragma unroll
        for (int mi = 0; mi < MPW2; ++mi)
            #pragma unroll
            for (int n = 0; n < 4; ++n)
                #pragma unroll
                for (int r = 0; r < 4; ++r) C2[mi][n][r] = bbv[mi][r];
        #pragma unroll
        for (int pk = 0; pk < NS2; ++pk)
            #pragma unroll
            for (int n = 0; n < 4; ++n) {
                const short* base = ys + (n*16 + c)*RSY + pk*32 + g*8;
                short8 yh = *(const short8*)base;
                short8 yl = *(const short8*)(base + H);
                #pragma unroll
                for (int mi = 0; mi < MPW2; ++mi) {
                    C2[mi][n] = __builtin_amdgcn_mfma_f32_16x16x32_bf16(wbh[mi][pk], yh, C2[mi][n], 0,0,0);
                    C2[mi][n] = __builtin_amdgcn_mfma_f32_16x16x32_bf16(wbl[mi][pk], yh, C2[mi][n], 0,0,0);
                    C2[mi][n] = __builtin_amdgcn_mfma_f32_16x16x32_bf16(wbh[mi][pk], yl, C2[mi][n], 0,0,0);
                }
            }
        // epilogue2: per-node max over 16 edge-cols, transpose, relu, store
        #pragma unroll
        for (int mi = 0; mi < MPW2; ++mi) {
            const int mt = mi*4 + w;
            #pragma unroll
            for (int n = 0; n < 4; ++n) {
                float4v v = C2[mi][n];
                #pragma unroll
                for (int r = 0; r < 4; ++r) {
                    float t = v[r];
                    t = fmaxf(t, __shfl_xor(t, 1));
                    t = fmaxf(t, __shfl_xor(t, 2));
                    t = fmaxf(t, __shfl_xor(t, 4));
                    t = fmaxf(t, __shfl_xor(t, 8));
                    v[r] = t;
                }
                // lane c should hold out-col (mt*16+c); it lives in lane
                // ((c>>2)*16 + c) reg (c&3)
                const int srcl = ((c >> 2) << 4) | c;
                float t0 = __shfl(v[0], srcl);
                float t1 = __shfl(v[1], srcl);
                float t2 = __shfl(v[2], srcl);
                float t3 = __shfl(v[3], srcl);
                const int rs = c & 3;
                float tv = rs == 0 ? t0 : rs == 1 ? t1 : rs == 2 ? t2 : t3;
                if (g == 0) {
                    const int node = tile*4 + n;
                    hout[(size_t)node*O + mt*16 + c] = fmaxf(tv, 0.f);
                }
            }
        }
        // no barrier needed here: next bar1 (after staging) orders ys reuse
    }
}

__global__ void zero_k(float* __restrict__ p, int n)
{
    const int i = blockIdx.x * 256 + threadIdx.x;
    if (i < n) p[i] = 0.f;
}

// batch is SORTED: register accumulation, one atomic per batch-change.
__global__ void pool_k(const float* __restrict__ h3, const int* __restrict__ batch,
                       float* __restrict__ pooled, float* __restrict__ counts)
{
    const int c    = threadIdx.x & 127;
    const int half = threadIdx.x >> 7;
    const int nbeg = blockIdx.x * 128 + half * 64;
    if (nbeg >= NNODES) return;
    const int nend = min(nbeg + 64, NNODES);

    int   cur = batch[nbeg];
    float acc = 0.f;
    int   runlen = 0;
    for (int n = nbeg; n < nend; ++n) {
        const int b = batch[n];
        if (b != cur) {
            atomicAdd(pooled + cur*128 + c, acc);
            if (c == 0) atomicAdd(counts + cur, (float)runlen);
            acc = 0.f; runlen = 0; cur = b;
        }
        acc += h3[(size_t)n * 128 + c];
        ++runlen;
    }
    atomicAdd(pooled + cur*128 + c, acc);
    if (c == 0) atomicAdd(counts + cur, (float)runlen);
}

__global__ void reg_k(const float* __restrict__ pooled, const float* __restrict__ counts,
                      const float* __restrict__ wr1, const float* __restrict__ br1,
                      const float* __restrict__ wr2, const float* __restrict__ br2,
                      float* __restrict__ out)
{
    const int b = blockIdx.x;     // 64 blocks
    const int h = threadIdx.x;    // 64 threads = hidden dim
    const float rc = 1.f / fmaxf(counts[b], 1.f);
    float acc = br1[h];
    #pragma unroll
    for (int k = 0; k < 128; ++k)
        acc = fmaf(pooled[b*128 + k] * rc, wr1[k*64 + h], acc);
    float v = acc * wr2[h];
    #pragma unroll
    for (int s = 1; s < 64; s <<= 1)
        v += __shfl_xor(v, s);
    if (h == 0) out[b] = 1.f / (1.f + expf(-(v + br2[0])));
}

extern "C" void kernel_launch(void* const* d_in, const int* in_sizes, int n_in,
                              void* d_out, int out_size, void* d_ws, size_t ws_size,
                              hipStream_t stream)
{
    const float* pos   = (const float*)d_in[0];
    const int*   eidx  = (const int*)d_in[1];    // [2,E]; row 0 = src
    const int*   batch = (const int*)d_in[2];
    // d_in[3] = timestep: unused by the reference
    const float *w1a = (const float*)d_in[4],  *b1a = (const float*)d_in[5];
    const float *w1b = (const float*)d_in[6],  *b1b = (const float*)d_in[7];
    const float *w2a = (const float*)d_in[8],  *b2a = (const float*)d_in[9];
    const float *w2b = (const float*)d_in[10], *b2b = (const float*)d_in[11];
    const float *w3a = (const float*)d_in[12], *b3a = (const float*)d_in[13];
    const float *w3b = (const float*)d_in[14], *b3b = (const float*)d_in[15];
    const float *wr1 = (const float*)d_in[16], *br1 = (const float*)d_in[17];
    const float *wr2 = (const float*)d_in[18], *br2 = (const float*)d_in[19];
    const int* srcArr = eidx;                    // row 0

    float* ws     = (float*)d_ws;
    float* h1     = ws;                                  // N*64
    float* h2     = h1 + (size_t)NNODES * 64;            // N*64
    float* h3     = h2 + (size_t)NNODES * 64;            // N*128
    float* pooled = h3 + (size_t)NNODES * 128;           // B*128
    float* counts = pooled + NBATCH * 128;               // B
    float* out    = (float*)d_out;

    const dim3 blk(256);
    layer_mfma<3,  64, 64 ><<<1536, blk, 0, stream>>>(pos, pos, srcArr, w1a, b1a, w1b, b1b, h1);
    layer_mfma<64, 64, 64 ><<< 768, blk, 0, stream>>>(h1,  pos, srcArr, w2a, b2a, w2b, b2b, h2);
    layer_mfma<64, 128,128><<< 512, blk, 0, stream>>>(h2,  pos, srcArr, w3a, b3a, w3b, b3b, h3);
    zero_k<<<(NBATCH*128 + NBATCH + 255)/256, blk, 0, stream>>>(pooled, NBATCH*128 + NBATCH);
    pool_k<<<(NNODES + 127)/128, blk, 0, stream>>>(h3, batch, pooled, counts);
    reg_k <<<NBATCH, dim3(64), 0, stream>>>(pooled, counts, wr1, br1, wr2, br2, out);
}

// Round 4
// 725.041 us; speedup vs baseline: 4.5552x; 1.1988x over previous
//
#include <hip/hip_runtime.h>
#include <math.h>

#define NNODES 100000
#define NEDGES 1600000
#define NBATCH 64
#define NTILES (NEDGES/64)   // 25000 tiles of 64 edges (4 nodes)

typedef __attribute__((ext_vector_type(8))) short  short8;
typedef __attribute__((ext_vector_type(4))) short  short4v;
typedef __attribute__((ext_vector_type(4))) float  float4v;

__device__ __forceinline__ short f2bf(float f) {           // RTNE fp32->bf16
    unsigned u = __builtin_bit_cast(unsigned, f);
    u += 0x7fffu + ((u >> 16) & 1u);
    return (short)(u >> 16);
}
__device__ __forceinline__ float b2f(short s) {
    unsigned u = ((unsigned)(unsigned short)s) << 16;
    return __builtin_bit_cast(float, u);
}

// max with a row_ror DPP operand: pure-VALU cross-lane (16-lane row rotate).
// Replaces ds_swizzle-based __shfl_xor -> keeps the LDS pipe free for MFMA
// operand reads. GCNDPPCombine fuses mov_dpp+max into v_max_f32_dpp.
template<int CTRL>
__device__ __forceinline__ float maxror(float v) {
    int t = __builtin_amdgcn_update_dpp(0, __builtin_bit_cast(int, v),
                                        CTRL, 0xf, 0xf, true);
    return fmaxf(v, __builtin_bit_cast(float, t));
}
__device__ __forceinline__ float red16max(float v) {
    v = maxror<0x128>(v);   // row_ror:8
    v = maxror<0x124>(v);   // row_ror:4
    v = maxror<0x122>(v);   // row_ror:2
    v = maxror<0x121>(v);   // row_ror:1
    return v;               // all 16 lanes of the row now hold the max
}

// Split-bf16 MFMA layer. Orientation swapped: A = W^T (M = out-dim), B = x^T
// (N = edges). D lane layout (m89-verified): col(=edge) = lane&15,
// row(=out) = (lane>>4)*4 + reg. Weights held in register frags for the whole
// block (persistent grid-stride loop); only activations stream through LDS.
// Precision: w = wh+wl, x = xh+xl (bf16 hi/lo); accumulate wh*xh + wl*xh +
// wh*xl in fp32 -> ~2^-17 relative error.
template<int CIN, int H, int O>
__global__ __launch_bounds__(256, 2)
void layer_mfma(const float* __restrict__ hin, const float* __restrict__ pos,
                const int* __restrict__ srcArr,
                const float* __restrict__ wa, const float* __restrict__ ba,
                const float* __restrict__ wb, const float* __restrict__ bb,
                float* __restrict__ hout)
{
    constexpr int K1   = CIN + 3;
    constexpr int S1   = ((K1 + 31) / 32) * 32;  // padded K of GEMM1
    constexpr int NS1  = S1 / 32;                // phys k-steps GEMM1
    constexpr int MPW1 = H / 64;                 // m-tiles per wave, GEMM1
    constexpr int NS2  = H / 32;                 // phys k-steps GEMM2
    constexpr int MPW2 = O / 64;
    constexpr int RSX  = 2 * S1 + 8;             // x' row stride (shorts)
    constexpr int RSY  = 2 * H + 8;

    __shared__ short smem[64 * RSX + 64 * RSY];
    short* xs = smem;            // [64 edges][xh(S1) | xl(S1) | pad]
    short* ys = smem + 64 * RSX; // [64 edges][yh(H)  | yl(H)  | pad]

    const int tid  = threadIdx.x;
    const int lane = tid & 63;
    const int w    = tid >> 6;   // wave id 0..3
    const int g    = lane >> 4;  // k-group
    const int c    = lane & 15;

    // Zero all of LDS once: K-pad columns must read as 0; data columns are
    // rewritten every tile.
    {
        short4v z4 = (short4v)0;
        for (int i = tid; i < (64*RSX + 64*RSY)/4; i += 256)
            ((short4v*)smem)[i] = z4;
    }

    // ---- build persistent weight fragments (A-operand: row = lane&15) ----
    short8 wah[MPW1][NS1], wal[MPW1][NS1];
    float  bav[MPW1][4];
    #pragma unroll
    for (int mi = 0; mi < MPW1; ++mi) {
        const int mt = mi*4 + w;
        const int h  = mt*16 + c;
        #pragma unroll
        for (int pk = 0; pk < NS1; ++pk) {
            short8 fh, fl;
            #pragma unroll
            for (int j = 0; j < 8; ++j) {
                const int k = pk*32 + g*8 + j;
                float f = (k < K1) ? wa[k*H + h] : 0.f;
                short hi = f2bf(f);
                fh[j] = hi;
                fl[j] = f2bf(f - b2f(hi));
            }
            wah[mi][pk] = fh; wal[mi][pk] = fl;
        }
        #pragma unroll
        for (int r = 0; r < 4; ++r) bav[mi][r] = ba[mt*16 + g*4 + r];
    }
    short8 wbh[MPW2][NS2], wbl[MPW2][NS2];
    float  bbv[MPW2][4];
    #pragma unroll
    for (int mi = 0; mi < MPW2; ++mi) {
        const int mt = mi*4 + w;
        const int o  = mt*16 + c;
        #pragma unroll
        for (int pk = 0; pk < NS2; ++pk) {
            short8 fh, fl;
            #pragma unroll
            for (int j = 0; j < 8; ++j) {
                const int k = pk*32 + g*8 + j;   // k < H always
                float f = wb[k*O + o];
                short hi = f2bf(f);
                fh[j] = hi;
                fl[j] = f2bf(f - b2f(hi));
            }
            wbh[mi][pk] = fh; wbl[mi][pk] = fl;
        }
        #pragma unroll
        for (int r = 0; r < 4; ++r) bbv[mi][r] = bb[mt*16 + g*4 + r];
    }
    __syncthreads();

    const int e   = tid & 63;    // edge-in-tile this thread stages
    const int rep = tid >> 6;

    for (int tile = blockIdx.x; tile < NTILES; tile += gridDim.x) {
        // ---- stage x' = split(concat(h[src], pos[src]-pos[dst])) ----
        {
            const int edge = tile*64 + e;
            const int src  = srcArr[edge];
            const int node = edge >> 4;
            if constexpr (CIN == 3) {
                if (rep == 0) {
                    float v[6];
                    v[0] = pos[src*3+0]; v[1] = pos[src*3+1]; v[2] = pos[src*3+2];
                    v[3] = v[0] - pos[node*3+0];
                    v[4] = v[1] - pos[node*3+1];
                    v[5] = v[2] - pos[node*3+2];
                    short4v h0, l0, h1, l1;
                    #pragma unroll
                    for (int j = 0; j < 4; ++j) { short hi=f2bf(v[j]); h0[j]=hi; l0[j]=f2bf(v[j]-b2f(hi)); }
                    #pragma unroll
                    for (int j = 0; j < 2; ++j) { short hi=f2bf(v[4+j]); h1[j]=hi; l1[j]=f2bf(v[4+j]-b2f(hi)); }
                    h1[2]=0; h1[3]=0; l1[2]=0; l1[3]=0;
                    *(short4v*)(xs + e*RSX + 0)      = h0;
                    *(short4v*)(xs + e*RSX + 4)      = h1;
                    *(short4v*)(xs + e*RSX + S1 + 0) = l0;
                    *(short4v*)(xs + e*RSX + S1 + 4) = l1;
                }
            } else {
                #pragma unroll
                for (int i = 0; i < CIN/16; ++i) {
                    const int cch = rep + 4*i;           // float4 chunk of h-row
                    float4v v = *(const float4v*)(hin + (size_t)src*CIN + cch*4);
                    short4v hv, lv;
                    #pragma unroll
                    for (int j = 0; j < 4; ++j) { short hi=f2bf(v[j]); hv[j]=hi; lv[j]=f2bf(v[j]-b2f(hi)); }
                    *(short4v*)(xs + e*RSX + cch*4)      = hv;
                    *(short4v*)(xs + e*RSX + S1 + cch*4) = lv;
                }
                if (rep == 0) {
                    float d0 = pos[src*3+0]-pos[node*3+0];
                    float d1 = pos[src*3+1]-pos[node*3+1];
                    float d2 = pos[src*3+2]-pos[node*3+2];
                    short4v hv, lv; short hi;
                    hi=f2bf(d0); hv[0]=hi; lv[0]=f2bf(d0-b2f(hi));
                    hi=f2bf(d1); hv[1]=hi; lv[1]=f2bf(d1-b2f(hi));
                    hi=f2bf(d2); hv[2]=hi; lv[2]=f2bf(d2-b2f(hi));
                    hv[3]=0; lv[3]=0;
                    *(short4v*)(xs + e*RSX + CIN)      = hv;
                    *(short4v*)(xs + e*RSX + S1 + CIN) = lv;
                }
            }
        }
        __syncthreads();

        // ---- GEMM1: C1[h][edge] = wa^T x + ba ----
        float4v C1[MPW1][4];
        #pragma unroll
        for (int mi = 0; mi < MPW1; ++mi)
            #pragma unroll
            for (int n = 0; n < 4; ++n)
                #pragma unroll
                for (int r = 0; r < 4; ++r) C1[mi][n][r] = bav[mi][r];
        #pragma unroll
        for (int pk = 0; pk < NS1; ++pk)
            #pragma unroll
            for (int n = 0; n < 4; ++n) {
                const short* base = xs + (n*16 + c)*RSX + pk*32 + g*8;
                short8 xh = *(const short8*)base;
                short8 xl = *(const short8*)(base + S1);
                #pragma unroll
                for (int mi = 0; mi < MPW1; ++mi) {
                    C1[mi][n] = __builtin_amdgcn_mfma_f32_16x16x32_bf16(wah[mi][pk], xh, C1[mi][n], 0,0,0);
                    C1[mi][n] = __builtin_amdgcn_mfma_f32_16x16x32_bf16(wal[mi][pk], xh, C1[mi][n], 0,0,0);
                    C1[mi][n] = __builtin_amdgcn_mfma_f32_16x16x32_bf16(wah[mi][pk], xl, C1[mi][n], 0,0,0);
                }
            }
        // epilogue1: relu -> split -> y' LDS (lane holds 4 consecutive h)
        #pragma unroll
        for (int mi = 0; mi < MPW1; ++mi) {
            const int mt = mi*4 + w;
            #pragma unroll
            for (int n = 0; n < 4; ++n) {
                short4v hv, lv;
                #pragma unroll
                for (int r = 0; r < 4; ++r) {
                    float y = fmaxf(C1[mi][n][r], 0.f);
                    short hi = f2bf(y);
                    hv[r] = hi; lv[r] = f2bf(y - b2f(hi));
                }
                short* yb = ys + (n*16 + c)*RSY + mt*16 + g*4;
                *(short4v*)yb       = hv;
                *(short4v*)(yb + H) = lv;
            }
        }
        __syncthreads();

        // ---- GEMM2: C2[o][edge] = wb^T y + bb ----
        float4v C2[MPW2][4];
        #pragma unroll
        for (int mi = 0; mi < MPW2; ++mi)
            #pragma unroll
            for (int n = 0; n < 4; ++n)
                #pragma unroll
                for (int r = 0; r < 4; ++r) C2[mi][n][r] = bbv[mi][r];
        #pragma unroll
        for (int pk = 0; pk < NS2; ++pk)
            #pragma unroll
            for (int n = 0; n < 4; ++n) {
                const short* base = ys + (n*16 + c)*RSY + pk*32 + g*8;
                short8 yh = *(const short8*)base;
                short8 yl = *(const short8*)(base + H);
                #pragma unroll
                for (int mi = 0; mi < MPW2; ++mi) {
                    C2[mi][n] = __builtin_amdgcn_mfma_f32_16x16x32_bf16(wbh[mi][pk], yh, C2[mi][n], 0,0,0);
                    C2[mi][n] = __builtin_amdgcn_mfma_f32_16x16x32_bf16(wbl[mi][pk], yh, C2[mi][n], 0,0,0);
                    C2[mi][n] = __builtin_amdgcn_mfma_f32_16x16x32_bf16(wbh[mi][pk], yl, C2[mi][n], 0,0,0);
                }
            }
        // epilogue2: per-node max over the 16 edge-cols via DPP rotate-reduce
        // (pure VALU, zero DS ops), then direct predicated coalesced store:
        // lanes c<4 of every g-group store channel mt*16 + g*4 + c.
        #pragma unroll
        for (int mi = 0; mi < MPW2; ++mi) {
            const int mt = mi*4 + w;
            #pragma unroll
            for (int n = 0; n < 4; ++n) {
                float v0 = red16max(C2[mi][n][0]);
                float v1 = red16max(C2[mi][n][1]);
                float v2 = red16max(C2[mi][n][2]);
                float v3 = red16max(C2[mi][n][3]);
                if (c < 4) {
                    float sv = (c == 0) ? v0 : (c == 1) ? v1 : (c == 2) ? v2 : v3;
                    const int node = tile*4 + n;
                    hout[(size_t)node*O + mt*16 + g*4 + c] = fmaxf(sv, 0.f);
                }
            }
        }
        // no barrier needed here: next bar (after staging) orders ys reuse
    }
}

__global__ void zero_k(float* __restrict__ p, int n)
{
    const int i = blockIdx.x * 256 + threadIdx.x;
    if (i < n) p[i] = 0.f;
}

// batch is SORTED: register accumulation, one atomic per batch-change.
__global__ void pool_k(const float* __restrict__ h3, const int* __restrict__ batch,
                       float* __restrict__ pooled, float* __restrict__ counts)
{
    const int c    = threadIdx.x & 127;
    const int half = threadIdx.x >> 7;
    const int nbeg = blockIdx.x * 128 + half * 64;
    if (nbeg >= NNODES) return;
    const int nend = min(nbeg + 64, NNODES);

    int   cur = batch[nbeg];
    float acc = 0.f;
    int   runlen = 0;
    for (int n = nbeg; n < nend; ++n) {
        const int b = batch[n];
        if (b != cur) {
            atomicAdd(pooled + cur*128 + c, acc);
            if (c == 0) atomicAdd(counts + cur, (float)runlen);
            acc = 0.f; runlen = 0; cur = b;
        }
        acc += h3[(size_t)n * 128 + c];
        ++runlen;
    }
    atomicAdd(pooled + cur*128 + c, acc);
    if (c == 0) atomicAdd(counts + cur, (float)runlen);
}

__global__ void reg_k(const float* __restrict__ pooled, const float* __restrict__ counts,
                      const float* __restrict__ wr1, const float* __restrict__ br1,
                      const float* __restrict__ wr2, const float* __restrict__ br2,
                      float* __restrict__ out)
{
    const int b = blockIdx.x;     // 64 blocks
    const int h = threadIdx.x;    // 64 threads = hidden dim
    const float rc = 1.f / fmaxf(counts[b], 1.f);
    float acc = br1[h];
    #pragma unroll
    for (int k = 0; k < 128; ++k)
        acc = fmaf(pooled[b*128 + k] * rc, wr1[k*64 + h], acc);
    float v = acc * wr2[h];
    #pragma unroll
    for (int s = 1; s < 64; s <<= 1)
        v += __shfl_xor(v, s);
    if (h == 0) out[b] = 1.f / (1.f + expf(-(v + br2[0])));
}

extern "C" void kernel_launch(void* const* d_in, const int* in_sizes, int n_in,
                              void* d_out, int out_size, void* d_ws, size_t ws_size,
                              hipStream_t stream)
{
    const float* pos   = (const float*)d_in[0];
    const int*   eidx  = (const int*)d_in[1];    // [2,E]; row 0 = src
    const int*   batch = (const int*)d_in[2];
    // d_in[3] = timestep: unused by the reference
    const float *w1a = (const float*)d_in[4],  *b1a = (const float*)d_in[5];
    const float *w1b = (const float*)d_in[6],  *b1b = (const float*)d_in[7];
    const float *w2a = (const float*)d_in[8],  *b2a = (const float*)d_in[9];
    const float *w2b = (const float*)d_in[10], *b2b = (const float*)d_in[11];
    const float *w3a = (const float*)d_in[12], *b3a = (const float*)d_in[13];
    const float *w3b = (const float*)d_in[14], *b3b = (const float*)d_in[15];
    const float *wr1 = (const float*)d_in[16], *br1 = (const float*)d_in[17];
    const float *wr2 = (const float*)d_in[18], *br2 = (const float*)d_in[19];
    const int* srcArr = eidx;                    // row 0

    float* ws     = (float*)d_ws;
    float* h1     = ws;                                  // N*64
    float* h2     = h1 + (size_t)NNODES * 64;            // N*64
    float* h3     = h2 + (size_t)NNODES * 64;            // N*128
    float* pooled = h3 + (size_t)NNODES * 128;           // B*128
    float* counts = pooled + NBATCH * 128;               // B
    float* out    = (float*)d_out;

    const dim3 blk(256);
    layer_mfma<3,  64, 64 ><<<1536, blk, 0, stream>>>(pos, pos, srcArr, w1a, b1a, w1b, b1b, h1);
    layer_mfma<64, 64, 64 ><<< 768, blk, 0, stream>>>(h1,  pos, srcArr, w2a, b2a, w2b, b2b, h2);
    layer_mfma<64, 128,128><<< 512, blk, 0, stream>>>(h2,  pos, srcArr, w3a, b3a, w3b, b3b, h3);
    zero_k<<<(NBATCH*128 + NBATCH + 255)/256, blk, 0, stream>>>(pooled, NBATCH*128 + NBATCH);
    pool_k<<<(NNODES + 127)/128, blk, 0, stream>>>(h3, batch, pooled, counts);
    reg_k <<<NBATCH, dim3(64), 0, stream>>>(pooled, counts, wr1, br1, wr2, br2, out);
}

// Round 5
// 616.066 us; speedup vs baseline: 5.3610x; 1.1769x over previous
//
#include <hip/hip_runtime.h>
#include <math.h>

#define NNODES 100000
#define NEDGES 1600000
#define NBATCH 64
#define NTILES (NEDGES/64)   // 25000 tiles of 64 edges (4 nodes)

typedef __attribute__((ext_vector_type(8))) short  short8;
typedef __attribute__((ext_vector_type(4))) short  short4v;
typedef __attribute__((ext_vector_type(4))) float  float4v;
typedef unsigned short ushort_t;

__device__ __forceinline__ short f2bf(float f) {           // RTNE fp32->bf16
    unsigned u = __builtin_bit_cast(unsigned, f);
    u += 0x7fffu + ((u >> 16) & 1u);
    return (short)(u >> 16);
}
__device__ __forceinline__ float b2f(short s) {
    unsigned u = ((unsigned)(unsigned short)s) << 16;
    return __builtin_bit_cast(float, u);
}

// max with a row_ror DPP operand: pure-VALU cross-lane (16-lane row rotate).
template<int CTRL>
__device__ __forceinline__ float maxror(float v) {
    int t = __builtin_amdgcn_update_dpp(0, __builtin_bit_cast(int, v),
                                        CTRL, 0xf, 0xf, true);
    return fmaxf(v, __builtin_bit_cast(float, t));
}
__device__ __forceinline__ float red16max(float v) {
    v = maxror<0x128>(v);   // row_ror:8
    v = maxror<0x124>(v);   // row_ror:4
    v = maxror<0x122>(v);   // row_ror:2
    v = maxror<0x121>(v);   // row_ror:1
    return v;               // all 16 lanes of the row now hold the max
}

// Split-bf16-weights MFMA layer, single-bf16 activations.
// A = W^T (M = out-dim), B = x^T (N = edges). D layout (m89): col(=edge) =
// lane&15, row(=out) = (lane>>4)*4 + reg. Weights (hi+lo bf16 planes) live in
// registers for the whole block; activations stream through LDS as ONE bf16
// plane. hin/hout are bf16 (producers write bf16 directly -> staging for the
// next layer is a pure copy, no split math).
template<int CIN, int H, int O>
__global__ __launch_bounds__(256, 3)
void layer_mfma(const ushort_t* __restrict__ hin, const float* __restrict__ pos,
                const int* __restrict__ srcArr,
                const float* __restrict__ wa, const float* __restrict__ ba,
                const float* __restrict__ wb, const float* __restrict__ bb,
                ushort_t* __restrict__ hout)
{
    constexpr int K1   = CIN + 3;
    constexpr int S1   = ((K1 + 31) / 32) * 32;  // padded K of GEMM1
    constexpr int NS1  = S1 / 32;
    constexpr int MPW1 = H / 64;
    constexpr int NS2  = H / 32;
    constexpr int MPW2 = O / 64;
    constexpr int RSX  = S1 + 8;                 // x row stride (shorts)
    constexpr int RSY  = H + 8;

    __shared__ short smem[64 * RSX + 64 * RSY];
    short* xs = smem;            // [64 edges][x bf16 (S1) | pad]
    short* ys = smem + 64 * RSX; // [64 edges][y bf16 (H)  | pad]

    const int tid  = threadIdx.x;
    const int lane = tid & 63;
    const int w    = tid >> 6;   // wave id 0..3
    const int g    = lane >> 4;  // k-group
    const int c    = lane & 15;

    // Zero all of LDS once: K-pad columns must read as 0.
    {
        short4v z4 = (short4v)0;
        for (int i = tid; i < (64*RSX + 64*RSY)/4; i += 256)
            ((short4v*)smem)[i] = z4;
    }

    // ---- persistent weight fragments (A-operand: row = lane&15) ----
    short8 wah[MPW1][NS1], wal[MPW1][NS1];
    float  bav[MPW1][4];
    #pragma unroll
    for (int mi = 0; mi < MPW1; ++mi) {
        const int mt = mi*4 + w;
        const int h  = mt*16 + c;
        #pragma unroll
        for (int pk = 0; pk < NS1; ++pk) {
            short8 fh, fl;
            #pragma unroll
            for (int j = 0; j < 8; ++j) {
                const int k = pk*32 + g*8 + j;
                float f = (k < K1) ? wa[k*H + h] : 0.f;
                short hi = f2bf(f);
                fh[j] = hi;
                fl[j] = f2bf(f - b2f(hi));
            }
            wah[mi][pk] = fh; wal[mi][pk] = fl;
        }
        #pragma unroll
        for (int r = 0; r < 4; ++r) bav[mi][r] = ba[mt*16 + g*4 + r];
    }
    short8 wbh[MPW2][NS2], wbl[MPW2][NS2];
    float  bbv[MPW2][4];
    #pragma unroll
    for (int mi = 0; mi < MPW2; ++mi) {
        const int mt = mi*4 + w;
        const int o  = mt*16 + c;
        #pragma unroll
        for (int pk = 0; pk < NS2; ++pk) {
            short8 fh, fl;
            #pragma unroll
            for (int j = 0; j < 8; ++j) {
                const int k = pk*32 + g*8 + j;   // k < H always
                float f = wb[k*O + o];
                short hi = f2bf(f);
                fh[j] = hi;
                fl[j] = f2bf(f - b2f(hi));
            }
            wbh[mi][pk] = fh; wbl[mi][pk] = fl;
        }
        #pragma unroll
        for (int r = 0; r < 4; ++r) bbv[mi][r] = bb[mt*16 + g*4 + r];
    }
    __syncthreads();

    const int e   = tid & 63;    // edge-in-tile this thread stages
    const int rep = tid >> 6;

    for (int tile = blockIdx.x; tile < NTILES; tile += gridDim.x) {
        // ---- stage x = bf16(concat(h[src], pos[src]-pos[dst])) ----
        {
            const int edge = tile*64 + e;
            const int src  = srcArr[edge];
            const int node = edge >> 4;
            if constexpr (CIN == 3) {
                if (rep == 0) {
                    float v[6];
                    v[0] = pos[src*3+0]; v[1] = pos[src*3+1]; v[2] = pos[src*3+2];
                    v[3] = v[0] - pos[node*3+0];
                    v[4] = v[1] - pos[node*3+1];
                    v[5] = v[2] - pos[node*3+2];
                    short8 hv;
                    #pragma unroll
                    for (int j = 0; j < 6; ++j) hv[j] = f2bf(v[j]);
                    hv[6] = 0; hv[7] = 0;
                    *(short8*)(xs + e*RSX) = hv;
                }
            } else {
                // pure copy: hin is already bf16 (producer rounded once)
                const ushort_t* hrow = hin + (size_t)src * CIN;
                #pragma unroll
                for (int i = 0; i < CIN/32; ++i) {
                    short8 v0 = *(const short8*)(hrow + rep*16 + i*64 + 0);
                    short8 v1 = *(const short8*)(hrow + rep*16 + i*64 + 8);
                    *(short8*)(xs + e*RSX + rep*16 + i*64 + 0) = v0;
                    *(short8*)(xs + e*RSX + rep*16 + i*64 + 8) = v1;
                }
                if (rep == 0) {
                    float d0 = pos[src*3+0]-pos[node*3+0];
                    float d1 = pos[src*3+1]-pos[node*3+1];
                    float d2 = pos[src*3+2]-pos[node*3+2];
                    short8 hv;
                    hv[0]=f2bf(d0); hv[1]=f2bf(d1); hv[2]=f2bf(d2);
                    hv[3]=0; hv[4]=0; hv[5]=0; hv[6]=0; hv[7]=0;
                    *(short8*)(xs + e*RSX + CIN) = hv;   // CIN*2 bytes: 16B aligned
                }
            }
        }
        __syncthreads();

        // ---- GEMM1: C1[h][edge] = (wah+wal)^T x + ba ----
        float4v C1[MPW1][4];
        #pragma unroll
        for (int mi = 0; mi < MPW1; ++mi)
            #pragma unroll
            for (int n = 0; n < 4; ++n)
                #pragma unroll
                for (int r = 0; r < 4; ++r) C1[mi][n][r] = bav[mi][r];
        #pragma unroll
        for (int pk = 0; pk < NS1; ++pk)
            #pragma unroll
            for (int n = 0; n < 4; ++n) {
                short8 xh = *(const short8*)(xs + (n*16 + c)*RSX + pk*32 + g*8);
                #pragma unroll
                for (int mi = 0; mi < MPW1; ++mi) {
                    C1[mi][n] = __builtin_amdgcn_mfma_f32_16x16x32_bf16(wah[mi][pk], xh, C1[mi][n], 0,0,0);
                    C1[mi][n] = __builtin_amdgcn_mfma_f32_16x16x32_bf16(wal[mi][pk], xh, C1[mi][n], 0,0,0);
                }
            }
        // epilogue1: relu -> bf16 -> y LDS (lane holds 4 consecutive h)
        #pragma unroll
        for (int mi = 0; mi < MPW1; ++mi) {
            const int mt = mi*4 + w;
            #pragma unroll
            for (int n = 0; n < 4; ++n) {
                short4v hv;
                #pragma unroll
                for (int r = 0; r < 4; ++r)
                    hv[r] = f2bf(fmaxf(C1[mi][n][r], 0.f));
                *(short4v*)(ys + (n*16 + c)*RSY + mt*16 + g*4) = hv;
            }
        }
        __syncthreads();

        // ---- GEMM2: C2[o][edge] = (wbh+wbl)^T y + bb ----
        float4v C2[MPW2][4];
        #pragma unroll
        for (int mi = 0; mi < MPW2; ++mi)
            #pragma unroll
            for (int n = 0; n < 4; ++n)
                #pragma unroll
                for (int r = 0; r < 4; ++r) C2[mi][n][r] = bbv[mi][r];
        #pragma unroll
        for (int pk = 0; pk < NS2; ++pk)
            #pragma unroll
            for (int n = 0; n < 4; ++n) {
                short8 yh = *(const short8*)(ys + (n*16 + c)*RSY + pk*32 + g*8);
                #pragma unroll
                for (int mi = 0; mi < MPW2; ++mi) {
                    C2[mi][n] = __builtin_amdgcn_mfma_f32_16x16x32_bf16(wbh[mi][pk], yh, C2[mi][n], 0,0,0);
                    C2[mi][n] = __builtin_amdgcn_mfma_f32_16x16x32_bf16(wbl[mi][pk], yh, C2[mi][n], 0,0,0);
                }
            }
        // epilogue2: per-node max via DPP rotate-reduce (zero DS ops); lanes
        // c<4 of every g-row store channel mt*16 + g*4 + c as bf16.
        #pragma unroll
        for (int mi = 0; mi < MPW2; ++mi) {
            const int mt = mi*4 + w;
            #pragma unroll
            for (int n = 0; n < 4; ++n) {
                float v0 = red16max(C2[mi][n][0]);
                float v1 = red16max(C2[mi][n][1]);
                float v2 = red16max(C2[mi][n][2]);
                float v3 = red16max(C2[mi][n][3]);
                if (c < 4) {
                    float sv = (c == 0) ? v0 : (c == 1) ? v1 : (c == 2) ? v2 : v3;
                    const int node = tile*4 + n;
                    hout[(size_t)node*O + mt*16 + g*4 + c] = (ushort_t)f2bf(fmaxf(sv, 0.f));
                }
            }
        }
        // no barrier needed here: next barrier (after staging) orders ys reuse
    }
}

__global__ void zero_k(float* __restrict__ p, int n)
{
    const int i = blockIdx.x * 256 + threadIdx.x;
    if (i < n) p[i] = 0.f;
}

// batch is SORTED: register accumulation, one atomic per batch-change.
__global__ void pool_k(const ushort_t* __restrict__ h3, const int* __restrict__ batch,
                       float* __restrict__ pooled, float* __restrict__ counts)
{
    const int c    = threadIdx.x & 127;
    const int half = threadIdx.x >> 7;
    const int nbeg = blockIdx.x * 128 + half * 64;
    if (nbeg >= NNODES) return;
    const int nend = min(nbeg + 64, NNODES);

    int   cur = batch[nbeg];
    float acc = 0.f;
    int   runlen = 0;
    for (int n = nbeg; n < nend; ++n) {
        const int b = batch[n];
        if (b != cur) {
            atomicAdd(pooled + cur*128 + c, acc);
            if (c == 0) atomicAdd(counts + cur, (float)runlen);
            acc = 0.f; runlen = 0; cur = b;
        }
        acc += b2f((short)h3[(size_t)n * 128 + c]);
        ++runlen;
    }
    atomicAdd(pooled + cur*128 + c, acc);
    if (c == 0) atomicAdd(counts + cur, (float)runlen);
}

__global__ void reg_k(const float* __restrict__ pooled, const float* __restrict__ counts,
                      const float* __restrict__ wr1, const float* __restrict__ br1,
                      const float* __restrict__ wr2, const float* __restrict__ br2,
                      float* __restrict__ out)
{
    const int b = blockIdx.x;     // 64 blocks
    const int h = threadIdx.x;    // 64 threads = hidden dim
    const float rc = 1.f / fmaxf(counts[b], 1.f);
    float acc = br1[h];
    #pragma unroll
    for (int k = 0; k < 128; ++k)
        acc = fmaf(pooled[b*128 + k] * rc, wr1[k*64 + h], acc);
    float v = acc * wr2[h];
    #pragma unroll
    for (int s = 1; s < 64; s <<= 1)
        v += __shfl_xor(v, s);
    if (h == 0) out[b] = 1.f / (1.f + expf(-(v + br2[0])));
}

extern "C" void kernel_launch(void* const* d_in, const int* in_sizes, int n_in,
                              void* d_out, int out_size, void* d_ws, size_t ws_size,
                              hipStream_t stream)
{
    const float* pos   = (const float*)d_in[0];
    const int*   eidx  = (const int*)d_in[1];    // [2,E]; row 0 = src
    const int*   batch = (const int*)d_in[2];
    // d_in[3] = timestep: unused by the reference
    const float *w1a = (const float*)d_in[4],  *b1a = (const float*)d_in[5];
    const float *w1b = (const float*)d_in[6],  *b1b = (const float*)d_in[7];
    const float *w2a = (const float*)d_in[8],  *b2a = (const float*)d_in[9];
    const float *w2b = (const float*)d_in[10], *b2b = (const float*)d_in[11];
    const float *w3a = (const float*)d_in[12], *b3a = (const float*)d_in[13];
    const float *w3b = (const float*)d_in[14], *b3b = (const float*)d_in[15];
    const float *wr1 = (const float*)d_in[16], *br1 = (const float*)d_in[17];
    const float *wr2 = (const float*)d_in[18], *br2 = (const float*)d_in[19];
    const int* srcArr = eidx;                    // row 0

    // bf16 hidden planes in workspace
    ushort_t* h1 = (ushort_t*)d_ws;                          // N*64 bf16
    ushort_t* h2 = h1 + (size_t)NNODES * 64;                 // N*64 bf16
    ushort_t* h3 = h2 + (size_t)NNODES * 64;                 // N*128 bf16
    float* pooled = (float*)(h3 + (size_t)NNODES * 128);     // B*128 f32
    float* counts = pooled + NBATCH * 128;                   // B
    float* out    = (float*)d_out;

    const dim3 blk(256);
    layer_mfma<3,  64, 64 ><<<1024, blk, 0, stream>>>(nullptr, pos, srcArr, w1a, b1a, w1b, b1b, h1);
    layer_mfma<64, 64, 64 ><<<1024, blk, 0, stream>>>(h1,      pos, srcArr, w2a, b2a, w2b, b2b, h2);
    layer_mfma<64, 128,128><<< 768, blk, 0, stream>>>(h2,      pos, srcArr, w3a, b3a, w3b, b3b, h3);
    zero_k<<<(NBATCH*128 + NBATCH + 255)/256, blk, 0, stream>>>(pooled, NBATCH*128 + NBATCH);
    pool_k<<<(NNODES + 127)/128, blk, 0, stream>>>(h3, batch, pooled, counts);
    reg_k <<<NBATCH, dim3(64), 0, stream>>>(pooled, counts, wr1, br1, wr2, br2, out);
}